// Round 6
// baseline (95.471 us; speedup 1.0000x reference)
//
#include <hip/hip_runtime.h>
#include <hip/hip_bf16.h>

#define N 4096
#define D 768
#define NK2 12   // D/64 K-steps (BK=64)

typedef float f32x4 __attribute__((ext_vector_type(4)));
typedef unsigned long u64x2 __attribute__((ext_vector_type(2)));

typedef __attribute__((address_space(3))) unsigned int as3_uint;
typedef const __attribute__((address_space(1))) unsigned int as1_uint;

__device__ __forceinline__ void gload16(const void* g, void* l) {
    __builtin_amdgcn_global_load_lds((as1_uint*)g, (as3_uint*)l, 16, 0, 0);
}

// Tiled fp8 global layout (per array, per 32-row group = 24 tiles x 1024B):
//   tile(rg, kt) at (rg*24 + kt)*1024; within tile byte = l*16 + h*8 + ko,
//   l = (R%16) + 16*((k%32)>>3), h = (R>>4)&1, ko = k&7.
// Staging is lane-linear 16B; fragment reads are ds_read_b128 at base+lane*16
// (bank-uniform, conflict-free), each yielding TWO mfma operands.

// ---------------- normalize: f32 [N][D] -> fp8 tiled, row L2-normalized ------
__global__ __launch_bounds__(256) void norm4(const float* __restrict__ x0,
                                             const float* __restrict__ x1,
                                             const float* __restrict__ x2,
                                             const float* __restrict__ x3,
                                             unsigned char* __restrict__ o) {
    int a = blockIdx.y;
    const float* x = (a == 0) ? x0 : (a == 1) ? x1 : (a == 2) ? x2 : x3;
    unsigned char* out = o + (size_t)a * N * D;
    int i0 = blockIdx.x * 32;                 // 32-row group
    __shared__ __align__(16) unsigned char tile[24576];
    int t = threadIdx.x, lane = t & 63, w = t >> 6;

    for (int rr = 0; rr < 8; ++rr) {
        int R = i0 + w * 8 + rr;
        const f32x4* xr = (const f32x4*)(x + (size_t)R * D);
        f32x4 v0 = xr[lane * 2], v1 = xr[lane * 2 + 1];
        f32x4 v2 = {}, v3 = {};
        if (lane < 32) { v2 = xr[128 + lane * 2]; v3 = xr[128 + lane * 2 + 1]; }
        float ss = v0[0]*v0[0] + v0[1]*v0[1] + v0[2]*v0[2] + v0[3]*v0[3]
                 + v1[0]*v1[0] + v1[1]*v1[1] + v1[2]*v1[2] + v1[3]*v1[3]
                 + v2[0]*v2[0] + v2[1]*v2[1] + v2[2]*v2[2] + v2[3]*v2[3]
                 + v3[0]*v3[0] + v3[1]*v3[1] + v3[2]*v3[2] + v3[3]*v3[3];
        #pragma unroll
        for (int m = 1; m < 64; m <<= 1) ss += __shfl_xor(ss, m);
        float s = 1.0f / fmaxf(sqrtf(ss), 1e-8f);

        {
            unsigned int wlo = __builtin_amdgcn_cvt_pk_fp8_f32(v0[0]*s, v0[1]*s, 0, false) & 0xffff;
            unsigned int whi = __builtin_amdgcn_cvt_pk_fp8_f32(v0[2]*s, v0[3]*s, 0, false) & 0xffff;
            unsigned int w0 = wlo | (whi << 16);
            wlo = __builtin_amdgcn_cvt_pk_fp8_f32(v1[0]*s, v1[1]*s, 0, false) & 0xffff;
            whi = __builtin_amdgcn_cvt_pk_fp8_f32(v1[2]*s, v1[3]*s, 0, false) & 0xffff;
            unsigned int w1 = wlo | (whi << 16);
            int g = lane;
            int off = (g >> 2) * 1024 + ((R & 15) + ((g & 3) << 4)) * 16 + (((R >> 4) & 1) << 3);
            *(uint2*)(tile + off) = make_uint2(w0, w1);
        }
        if (lane < 32) {
            unsigned int wlo = __builtin_amdgcn_cvt_pk_fp8_f32(v2[0]*s, v2[1]*s, 0, false) & 0xffff;
            unsigned int whi = __builtin_amdgcn_cvt_pk_fp8_f32(v2[2]*s, v2[3]*s, 0, false) & 0xffff;
            unsigned int w0 = wlo | (whi << 16);
            wlo = __builtin_amdgcn_cvt_pk_fp8_f32(v3[0]*s, v3[1]*s, 0, false) & 0xffff;
            whi = __builtin_amdgcn_cvt_pk_fp8_f32(v3[2]*s, v3[3]*s, 0, false) & 0xffff;
            unsigned int w1 = wlo | (whi << 16);
            int g = 64 + lane;
            int off = (g >> 2) * 1024 + ((R & 15) + ((g & 3) << 4)) * 16 + (((R >> 4) & 1) << 3);
            *(uint2*)(tile + off) = make_uint2(w0, w1);
        }
    }
    __syncthreads();
    unsigned char* dst = out + (size_t)(i0 >> 5) * 24576;
    #pragma unroll
    for (int i = 0; i < 6; ++i)
        ((int4*)dst)[t + i * 256] = ((const int4*)tile)[t + i * 256];
}

// ---------------- fused dual-GEMM (fp8, tiled) + softmax-KL partials ---------
// 128x128 tile, BK=64, 4 waves (2x2), wave tile 64x64 per gemm.
// LDS/buffer (32KB): As@0 (k0@0,k1@4096), At@8192, Bs@16384, Bt@24576; dbuf 64KB.
// One merged phase per K-step: issue 8 gloads(k+1) -> vmcnt(8) -> barrier ->
// 16 ds_read_b128 -> 64 MFMA -> barrier. Counted vmcnt never drains in loop.

__global__ __launch_bounds__(256, 2) void fused_gemm(
        const unsigned char* __restrict__ Xs, const unsigned char* __restrict__ Ys,
        const unsigned char* __restrict__ Xt, const unsigned char* __restrict__ Yt,
        float* __restrict__ partial) {
    __shared__ __align__(16) char smem[65536];
    const int t = threadIdx.x;
    const int jb = blockIdx.x, ib = blockIdx.y;
    const int i0 = ib * 128;
    const int lane = t & 63, wid = t >> 6;
    const int wm = wid >> 1, wn = wid & 1;

    f32x4 acc_s[4][4] = {};
    f32x4 acc_t[4][4] = {};

    const size_t srcA = ((size_t)(ib * 4 + wid)) * 24576 + (size_t)(t & 63) * 16;
    const size_t srcB = ((size_t)(jb * 4 + wid)) * 24576 + (size_t)(t & 63) * 16;
    const unsigned char* gAs = Xs + srcA;
    const unsigned char* gAt = Xt + srcA;
    const unsigned char* gBs = Ys + srcB;
    const unsigned char* gBt = Yt + srcB;

    char* cur = smem;
    char* nxt = smem + 32768;
    const int sdst = t * 16;

    // issue 8 loads for K-step k into buffer dst (k-tiles 2k, 2k+1)
    #define ISSUE8(dst, k)  do {                                                 \
        int _off = (k) * 2048;                                                   \
        gload16(gAs + _off,        (dst) + sdst);                                \
        gload16(gAs + _off + 1024, (dst) + sdst + 4096);                         \
        gload16(gBs + _off,        (dst) + 16384 + sdst);                        \
        gload16(gBs + _off + 1024, (dst) + 16384 + sdst + 4096);                 \
        gload16(gAt + _off,        (dst) + 8192 + sdst);                         \
        gload16(gAt + _off + 1024, (dst) + 8192 + sdst + 4096);                  \
        gload16(gBt + _off,        (dst) + 24576 + sdst);                        \
        gload16(gBt + _off + 1024, (dst) + 24576 + sdst + 4096);                 \
    } while (0)

    ISSUE8(cur, 0);

    const int offA = wm * 2048 + lane * 16;            // within A region
    const int offB = 16384 + wn * 2048 + lane * 16;    // within Bs region

    #pragma unroll 1
    for (int k = 0; k < NK2; ++k) {
        if (k < NK2 - 1) {
            ISSUE8(nxt, k + 1);
            asm volatile("s_waitcnt vmcnt(8)" ::: "memory");   // k's 8 done, k+1's in flight
        } else {
            asm volatile("s_waitcnt vmcnt(0)" ::: "memory");   // peeled drain
        }
        __builtin_amdgcn_s_barrier();

        #pragma unroll
        for (int kk = 0; kk < 2; ++kk) {
            const char* c = cur + kk * 4096;
            u64x2 as01 = *(const u64x2*)(c + offA);
            u64x2 as23 = *(const u64x2*)(c + offA + 1024);
            u64x2 bs01 = *(const u64x2*)(c + offB);
            u64x2 bs23 = *(const u64x2*)(c + offB + 1024);
            u64x2 at01 = *(const u64x2*)(c + 8192 + offA);
            u64x2 at23 = *(const u64x2*)(c + 8192 + offA + 1024);
            u64x2 bt01 = *(const u64x2*)(c + 8192 + offB);
            u64x2 bt23 = *(const u64x2*)(c + 8192 + offB + 1024);
            long a_s[4] = {(long)as01[0], (long)as01[1], (long)as23[0], (long)as23[1]};
            long b_s[4] = {(long)bs01[0], (long)bs01[1], (long)bs23[0], (long)bs23[1]};
            long a_t[4] = {(long)at01[0], (long)at01[1], (long)at23[0], (long)at23[1]};
            long b_t[4] = {(long)bt01[0], (long)bt01[1], (long)bt23[0], (long)bt23[1]};
            __builtin_amdgcn_s_setprio(1);
            #pragma unroll
            for (int m = 0; m < 4; ++m)
                #pragma unroll
                for (int n = 0; n < 4; ++n)
                    acc_s[m][n] = __builtin_amdgcn_mfma_f32_16x16x32_fp8_fp8(a_s[m], b_s[n], acc_s[m][n], 0, 0, 0);
            #pragma unroll
            for (int m = 0; m < 4; ++m)
                #pragma unroll
                for (int n = 0; n < 4; ++n)
                    acc_t[m][n] = __builtin_amdgcn_mfma_f32_16x16x32_fp8_fp8(a_t[m], b_t[n], acc_t[m][n], 0, 0, 0);
            __builtin_amdgcn_s_setprio(0);
        }

        __builtin_amdgcn_s_barrier();
        char* tmp = cur; cur = nxt; nxt = tmp;
    }
    #undef ISSUE8

    // ---- epilogue: per-row partial stats over this block's 128 columns ----
    __syncthreads();
    float* part = (float*)smem;      // [2 wn][128 rows][4 stats]
    const int g = lane >> 4, cl = lane & 15;
    // halving-tree leaves lane cl holding sum of v[rev4(cl)]
    const int idx = ((cl & 1) << 3) | ((cl & 2) << 1) | ((cl & 4) >> 1) | ((cl & 8) >> 3);
    const int rsel = idx >> 2, ssel = idx & 3;
    const int rowbase = wm * 64 + g * 4 + rsel;

    #pragma unroll
    for (int m = 0; m < 4; ++m) {
        float v[16];
        #pragma unroll
        for (int i = 0; i < 16; ++i) v[i] = 0.f;
        #pragma unroll
        for (int n = 0; n < 4; ++n)
            #pragma unroll
            for (int rr = 0; rr < 4; ++rr) {
                float ls = 10.0f * acc_s[m][n][rr];
                float lt = 10.0f * acc_t[m][n][rr];
                float es = __expf(ls - 10.0f);
                float et = __expf(lt - 10.0f);
                v[rr * 4 + 0] += es;
                v[rr * 4 + 1] += et;
                v[rr * 4 + 2] += es * (ls - lt);
                v[rr * 4 + 3] += et * (lt - ls);
            }
        // halving tree across the 16-lane group: 16 values -> 1 per lane
        #pragma unroll
        for (int stage = 0; stage < 4; ++stage) {
            const int msk = 1 << stage, half = 8 >> stage;
            const bool hi = (lane & msk) != 0;
            #pragma unroll
            for (int i = 0; i < half; ++i) {
                float send = hi ? v[i] : v[i + half];
                float recv = __shfl_xor(send, msk);
                v[i] = (hi ? v[i + half] : v[i]) + recv;
            }
        }
        part[(wn * 128 + rowbase + m * 16) * 4 + ssel] = v[0];
    }
    __syncthreads();
    #pragma unroll
    for (int q = 0; q < 2; ++q) {
        int idx2 = t + q * 256;      // 512 slots = 128 rows x 4 stats
        int row = idx2 >> 2, s = idx2 & 3;
        float v = part[(0 * 128 + row) * 4 + s] + part[(1 * 128 + row) * 4 + s];
        partial[((size_t)jb * N + (i0 + row)) * 4 + s] = v;
    }
}

// ---------------- per-row finalize + block partial sums ----------------------
__global__ __launch_bounds__(256) void reduce_rows(const float* __restrict__ partial,
                                                   float* __restrict__ blocksum) {
    int row = blockIdx.x * 256 + threadIdx.x;
    float zs = 0.f, zt = 0.f, ws = 0.f, wt = 0.f;
    for (int jb = 0; jb < 32; ++jb) {
        const float* p = partial + ((size_t)jb * N + row) * 4;
        zs += p[0]; zt += p[1]; ws += p[2]; wt += p[3];
    }
    float ls_row = wt / zt - logf(zt) + logf(zs);
    float lt_row = ws / zs - logf(zs) + logf(zt);
    #pragma unroll
    for (int m = 1; m < 64; m <<= 1) {
        ls_row += __shfl_xor(ls_row, m);
        lt_row += __shfl_xor(lt_row, m);
    }
    __shared__ float rs[4], rt[4];
    int lane = threadIdx.x & 63, wid = threadIdx.x >> 6;
    if (lane == 0) { rs[wid] = ls_row; rt[wid] = lt_row; }
    __syncthreads();
    if (threadIdx.x == 0) {
        blocksum[blockIdx.x * 2]     = rs[0] + rs[1] + rs[2] + rs[3];
        blocksum[blockIdx.x * 2 + 1] = rt[0] + rt[1] + rt[2] + rt[3];
    }
}

__global__ void final_reduce(const float* __restrict__ blocksum, float* __restrict__ out) {
    float a = 0.f, b = 0.f;
    if (threadIdx.x < 16) { a = blocksum[threadIdx.x * 2]; b = blocksum[threadIdx.x * 2 + 1]; }
    #pragma unroll
    for (int m = 1; m < 16; m <<= 1) { a += __shfl_xor(a, m); b += __shfl_xor(b, m); }
    if (threadIdx.x == 0) {
        const float inv = 1.0f / 16777216.0f;   // 1/N^2
        out[0] = a * inv;
        out[1] = b * inv;
    }
}

extern "C" void kernel_launch(void* const* d_in, const int* in_sizes, int n_in,
                              void* d_out, int out_size, void* d_ws, size_t ws_size,
                              hipStream_t stream) {
    const float* zxs = (const float*)d_in[0];
    const float* zys = (const float*)d_in[1];
    const float* zxt = (const float*)d_in[2];
    const float* zyt = (const float*)d_in[3];

    char* ws = (char*)d_ws;
    const size_t A = (size_t)N * D;                   // bytes per fp8 array
    unsigned char* nb = (unsigned char*)ws;           // 4 normalized fp8 arrays (tiled)
    float* partial  = (float*)(ws + 4 * A);           // [32][N][4] f32 = 2 MB
    float* blocksum = (float*)(ws + 4 * A + (size_t)32 * N * 4 * sizeof(float));

    norm4<<<dim3(N / 32, 4), 256, 0, stream>>>(zxs, zys, zxt, zyt, nb);

    const unsigned char* Xs = nb;
    const unsigned char* Ys = nb + A;
    const unsigned char* Xt = nb + 2 * A;
    const unsigned char* Yt = nb + 3 * A;
    fused_gemm<<<dim3(32, 32), 256, 0, stream>>>(Xs, Ys, Xt, Yt, partial);

    reduce_rows<<<16, 256, 0, stream>>>(partial, blocksum);
    final_reduce<<<1, 64, 0, stream>>>(blocksum, (float*)d_out);
}

// Round 7
// 61.724 us; speedup vs baseline: 1.5467x; 1.5467x over previous
//
#include <hip/hip_runtime.h>
#include <hip/hip_bf16.h>

#define N 4096
#define D 768
#define NC 6    // D/128 K-chunks per gemm pass

typedef float f32x4 __attribute__((ext_vector_type(4)));
typedef int v8i __attribute__((ext_vector_type(8)));

typedef __attribute__((address_space(3))) unsigned int as3_uint;
typedef const __attribute__((address_space(1))) unsigned int as1_uint;

__device__ __forceinline__ void gload16(const void* g, void* l) {
    __builtin_amdgcn_global_load_lds((as1_uint*)g, (as3_uint*)l, 16, 0, 0);
}

// Tiled fp8 global layout for mfma_scale_f32_16x16x128_f8f6f4:
// frag-tile = 16 rows x 128 k = 2048B, index (R>>4, k>>7), per array
// [N/16][6] tiles. Within a tile: lane l = (R&15) + 16*((k&127)>>5) holds
// 32 contiguous k as 8 VGPRs; stored as two lane-linear 1024B halves:
//   byte = ((k&31)>=16 ? 1024 : 0) + l*16 + (k&15)
// -> ds_read_b128 at base+lane*16 and base+1024+lane*16: conflict-free,
//    and global_load_lds staging keeps dest = uniform + lane*16.

// ---------------- normalize: f32 [N][D] -> fp8 tiled, row L2-normalized ------
__global__ __launch_bounds__(256) void norm4(const float* __restrict__ x0,
                                             const float* __restrict__ x1,
                                             const float* __restrict__ x2,
                                             const float* __restrict__ x3,
                                             unsigned char* __restrict__ o) {
    int a = blockIdx.y;
    const float* x = (a == 0) ? x0 : (a == 1) ? x1 : (a == 2) ? x2 : x3;
    unsigned char* out = o + (size_t)a * N * D;
    int i0 = blockIdx.x * 32;                 // 32-row group
    __shared__ __align__(16) unsigned char tile[24576];
    int t = threadIdx.x, lane = t & 63, w = t >> 6;

    for (int rr = 0; rr < 8; ++rr) {
        int R = i0 + w * 8 + rr;
        const f32x4* xr = (const f32x4*)(x + (size_t)R * D);
        f32x4 v0 = xr[lane * 2], v1 = xr[lane * 2 + 1];
        f32x4 v2 = {}, v3 = {};
        if (lane < 32) { v2 = xr[128 + lane * 2]; v3 = xr[128 + lane * 2 + 1]; }
        float ss = v0[0]*v0[0] + v0[1]*v0[1] + v0[2]*v0[2] + v0[3]*v0[3]
                 + v1[0]*v1[0] + v1[1]*v1[1] + v1[2]*v1[2] + v1[3]*v1[3]
                 + v2[0]*v2[0] + v2[1]*v2[1] + v2[2]*v2[2] + v2[3]*v2[3]
                 + v3[0]*v3[0] + v3[1]*v3[1] + v3[2]*v3[2] + v3[3]*v3[3];
        #pragma unroll
        for (int m = 1; m < 64; m <<= 1) ss += __shfl_xor(ss, m);
        float s = 1.0f / fmaxf(sqrtf(ss), 1e-8f);

        // granule g: 8 bytes at k = g*8
        // off = ((lrg)*6 + (g>>4))*2048 + ((g>>1)&1)*1024
        //       + ((R&15) + 16*((g&15)>>2))*16 + (g&1)*8
        int lrg = (R >> 4) & 1;
        {
            unsigned int wlo = __builtin_amdgcn_cvt_pk_fp8_f32(v0[0]*s, v0[1]*s, 0, false) & 0xffff;
            unsigned int whi = __builtin_amdgcn_cvt_pk_fp8_f32(v0[2]*s, v0[3]*s, 0, false) & 0xffff;
            unsigned int w0 = wlo | (whi << 16);
            wlo = __builtin_amdgcn_cvt_pk_fp8_f32(v1[0]*s, v1[1]*s, 0, false) & 0xffff;
            whi = __builtin_amdgcn_cvt_pk_fp8_f32(v1[2]*s, v1[3]*s, 0, false) & 0xffff;
            unsigned int w1 = wlo | (whi << 16);
            int g = lane;
            int off = (lrg * 6 + (g >> 4)) * 2048 + ((g >> 1) & 1) * 1024
                    + ((R & 15) + 16 * ((g & 15) >> 2)) * 16 + (g & 1) * 8;
            *(uint2*)(tile + off) = make_uint2(w0, w1);
        }
        if (lane < 32) {
            unsigned int wlo = __builtin_amdgcn_cvt_pk_fp8_f32(v2[0]*s, v2[1]*s, 0, false) & 0xffff;
            unsigned int whi = __builtin_amdgcn_cvt_pk_fp8_f32(v2[2]*s, v2[3]*s, 0, false) & 0xffff;
            unsigned int w0 = wlo | (whi << 16);
            wlo = __builtin_amdgcn_cvt_pk_fp8_f32(v3[0]*s, v3[1]*s, 0, false) & 0xffff;
            whi = __builtin_amdgcn_cvt_pk_fp8_f32(v3[2]*s, v3[3]*s, 0, false) & 0xffff;
            unsigned int w1 = wlo | (whi << 16);
            int g = 64 + lane;
            int off = (lrg * 6 + (g >> 4)) * 2048 + ((g >> 1) & 1) * 1024
                    + ((R & 15) + 16 * ((g & 15) >> 2)) * 16 + (g & 1) * 8;
            *(uint2*)(tile + off) = make_uint2(w0, w1);
        }
    }
    __syncthreads();
    unsigned char* dst = out + (size_t)(i0 >> 5) * 24576;
    #pragma unroll
    for (int i = 0; i < 6; ++i)
        ((int4*)dst)[t + i * 256] = ((const int4*)tile)[t + i * 256];
}

// ---------------- one gemm pass: acc += A_blk(128) x B_blk(128)^T ------------
// BK=128 chunks, LDS buffer 32KB = A[8 tiles][2048] @0, B @16384; dbuf 64KB.
// Per chunk: issue 8 gloads(next) -> vmcnt(8) -> barrier -> 16 b128 reads ->
// 16 MFMA(K=128, scales=1.0) -> barrier. Counted vmcnt never drains in loop.
__device__ __forceinline__ void gemm_pass(const unsigned char* __restrict__ A,
                                          const unsigned char* __restrict__ B,
                                          char* smem, int ib, int jb, int t,
                                          f32x4 (&acc)[4][4]) {
    const int lane = t & 63, w = t >> 6;
    const int wm = w >> 1, wn = w & 1;

    const unsigned char* gA = A + (size_t)((ib * 8 + 2 * w) * 6) * 2048 + lane * 16;
    const unsigned char* gB = B + (size_t)((jb * 8 + 2 * w) * 6) * 2048 + lane * 16;
    char* cur = smem;
    char* nxt = smem + 32768;
    const int sd = w * 4096 + lane * 16;

    #define ISSUE(dst, c)  do {                                                  \
        const unsigned char* _a = gA + (c) * 2048;                               \
        gload16(_a,         (dst) + sd);                                         \
        gload16(_a + 1024,  (dst) + sd + 1024);                                  \
        gload16(_a + 12288, (dst) + sd + 2048);                                  \
        gload16(_a + 13312, (dst) + sd + 3072);                                  \
        const unsigned char* _b = gB + (c) * 2048;                               \
        gload16(_b,         (dst) + 16384 + sd);                                 \
        gload16(_b + 1024,  (dst) + 16384 + sd + 1024);                          \
        gload16(_b + 12288, (dst) + 16384 + sd + 2048);                          \
        gload16(_b + 13312, (dst) + 16384 + sd + 3072);                          \
    } while (0)

    ISSUE(cur, 0);

    #pragma unroll 1
    for (int c = 0; c < NC; ++c) {
        if (c < NC - 1) {
            ISSUE(nxt, c + 1);
            asm volatile("s_waitcnt vmcnt(8)" ::: "memory");
        } else {
            asm volatile("s_waitcnt vmcnt(0)" ::: "memory");
        }
        __builtin_amdgcn_s_barrier();

        v8i a[4], b[4];
        #pragma unroll
        for (int m = 0; m < 4; ++m) {
            const char* p = cur + (wm * 4 + m) * 2048 + lane * 16;
            int4 lo = *(const int4*)p;
            int4 hi = *(const int4*)(p + 1024);
            a[m] = (v8i){lo.x, lo.y, lo.z, lo.w, hi.x, hi.y, hi.z, hi.w};
        }
        #pragma unroll
        for (int n = 0; n < 4; ++n) {
            const char* p = cur + 16384 + (wn * 4 + n) * 2048 + lane * 16;
            int4 lo = *(const int4*)p;
            int4 hi = *(const int4*)(p + 1024);
            b[n] = (v8i){lo.x, lo.y, lo.z, lo.w, hi.x, hi.y, hi.z, hi.w};
        }
        __builtin_amdgcn_s_setprio(1);
        #pragma unroll
        for (int m = 0; m < 4; ++m)
            #pragma unroll
            for (int n = 0; n < 4; ++n)
                acc[m][n] = __builtin_amdgcn_mfma_scale_f32_16x16x128_f8f6f4(
                    a[m], b[n], acc[m][n], 0, 0, 0, 127, 0, 127);
        __builtin_amdgcn_s_setprio(0);
        __builtin_amdgcn_s_barrier();
        char* tmp = cur; cur = nxt; nxt = tmp;
    }
    #undef ISSUE
}

__global__ __launch_bounds__(256, 2) void fused_gemm(
        const unsigned char* __restrict__ Xs, const unsigned char* __restrict__ Ys,
        const unsigned char* __restrict__ Xt, const unsigned char* __restrict__ Yt,
        float* __restrict__ partial) {
    __shared__ __align__(16) char smem[65536];
    const int t = threadIdx.x;
    const int jb = blockIdx.x, ib = blockIdx.y;
    const int i0 = ib * 128;
    const int lane = t & 63, wid = t >> 6;
    const int wm = wid >> 1, wn = wid & 1;

    f32x4 acc_s[4][4] = {};
    f32x4 acc_t[4][4] = {};

    gemm_pass(Xs, Ys, smem, ib, jb, t, acc_s);
    gemm_pass(Xt, Yt, smem, ib, jb, t, acc_t);

    // ---- epilogue (R5-proven): per-row partials over this block's 128 cols --
    __syncthreads();
    float* part = (float*)smem;      // [2 wn][128 rows][4 stats]
    int g = lane >> 4, cl = lane & 15;

    #pragma unroll
    for (int m = 0; m < 4; ++m) {
        float st[4][4];
        #pragma unroll
        for (int r = 0; r < 4; ++r) { st[r][0] = 0.f; st[r][1] = 0.f; st[r][2] = 0.f; st[r][3] = 0.f; }
        #pragma unroll
        for (int n = 0; n < 4; ++n)
            #pragma unroll
            for (int r = 0; r < 4; ++r) {
                float ls = 10.0f * acc_s[m][n][r];
                float lt = 10.0f * acc_t[m][n][r];
                float es = __expf(ls - 10.0f);
                float et = __expf(lt - 10.0f);
                st[r][0] += es;
                st[r][1] += et;
                st[r][2] += es * (ls - lt);
                st[r][3] += et * (lt - ls);
            }
        #pragma unroll
        for (int r = 0; r < 4; ++r)
            #pragma unroll
            for (int s = 0; s < 4; ++s) {
                float v = st[r][s];
                v += __shfl_xor(v, 1);
                v += __shfl_xor(v, 2);
                v += __shfl_xor(v, 4);
                v += __shfl_xor(v, 8);
                st[r][s] = v;
            }
        if (cl == 0) {
            int row = wm * 64 + m * 16 + g * 4;
            #pragma unroll
            for (int r = 0; r < 4; ++r)
                #pragma unroll
                for (int s = 0; s < 4; ++s)
                    part[(wn * 128 + row + r) * 4 + s] = st[r][s];
        }
    }
    __syncthreads();
    #pragma unroll
    for (int q = 0; q < 2; ++q) {
        int idx = t + q * 256;
        int row = idx >> 2, s = idx & 3;
        float v = part[(0 * 128 + row) * 4 + s] + part[(1 * 128 + row) * 4 + s];
        partial[((size_t)jb * N + (i0 + row)) * 4 + s] = v;
    }
}

// ---------------- per-row finalize + block partial sums ----------------------
__global__ __launch_bounds__(256) void reduce_rows(const float* __restrict__ partial,
                                                   float* __restrict__ blocksum) {
    int row = blockIdx.x * 256 + threadIdx.x;
    float zs = 0.f, zt = 0.f, ws = 0.f, wt = 0.f;
    for (int jb = 0; jb < 32; ++jb) {
        const float* p = partial + ((size_t)jb * N + row) * 4;
        zs += p[0]; zt += p[1]; ws += p[2]; wt += p[3];
    }
    float ls_row = wt / zt - logf(zt) + logf(zs);
    float lt_row = ws / zs - logf(zs) + logf(zt);
    #pragma unroll
    for (int m = 1; m < 64; m <<= 1) {
        ls_row += __shfl_xor(ls_row, m);
        lt_row += __shfl_xor(lt_row, m);
    }
    __shared__ float rs[4], rt[4];
    int lane = threadIdx.x & 63, wid = threadIdx.x >> 6;
    if (lane == 0) { rs[wid] = ls_row; rt[wid] = lt_row; }
    __syncthreads();
    if (threadIdx.x == 0) {
        blocksum[blockIdx.x * 2]     = rs[0] + rs[1] + rs[2] + rs[3];
        blocksum[blockIdx.x * 2 + 1] = rt[0] + rt[1] + rt[2] + rt[3];
    }
}

__global__ void final_reduce(const float* __restrict__ blocksum, float* __restrict__ out) {
    float a = 0.f, b = 0.f;
    if (threadIdx.x < 16) { a = blocksum[threadIdx.x * 2]; b = blocksum[threadIdx.x * 2 + 1]; }
    #pragma unroll
    for (int m = 1; m < 16; m <<= 1) { a += __shfl_xor(a, m); b += __shfl_xor(b, m); }
    if (threadIdx.x == 0) {
        const float inv = 1.0f / 16777216.0f;   // 1/N^2
        out[0] = a * inv;
        out[1] = b * inv;
    }
}

extern "C" void kernel_launch(void* const* d_in, const int* in_sizes, int n_in,
                              void* d_out, int out_size, void* d_ws, size_t ws_size,
                              hipStream_t stream) {
    const float* zxs = (const float*)d_in[0];
    const float* zys = (const float*)d_in[1];
    const float* zxt = (const float*)d_in[2];
    const float* zyt = (const float*)d_in[3];

    char* ws = (char*)d_ws;
    const size_t A = (size_t)N * D;                   // bytes per fp8 array
    unsigned char* nb = (unsigned char*)ws;           // 4 normalized fp8 arrays (tiled)
    float* partial  = (float*)(ws + 4 * A);           // [32][N][4] f32 = 2 MB
    float* blocksum = (float*)(ws + 4 * A + (size_t)32 * N * 4 * sizeof(float));

    norm4<<<dim3(N / 32, 4), 256, 0, stream>>>(zxs, zys, zxt, zyt, nb);

    const unsigned char* Xs = nb;
    const unsigned char* Ys = nb + A;
    const unsigned char* Xt = nb + 2 * A;
    const unsigned char* Yt = nb + 3 * A;
    fused_gemm<<<dim3(32, 32), 256, 0, stream>>>(Xs, Ys, Xt, Yt, partial);

    reduce_rows<<<16, 256, 0, stream>>>(partial, blocksum);
    final_reduce<<<1, 64, 0, stream>>>(blocksum, (float*)d_out);
}